// Round 2
// baseline (496.932 us; speedup 1.0000x reference)
//
#include <hip/hip_runtime.h>
#include <hip/hip_cooperative_groups.h>

namespace cg = cooperative_groups;

#define D 1024
#define T 2048
#define BATCH 4
#define NB 1024          // 4 blocks/CU x 256 CUs -> exactly co-resident

// workspace float offsets
#define WS_WBAR  0       // 1024 : mean_e Wk[e,d]
#define WS_BBAR  1024    // 1    : mean(bk)
#define WS_KMEAN 2048    // 8192 : kmean[b*T+t]
#define WS_XW    10240   // 4096 : sum_t w[b,t]*x[b,t,d]
#define WS_O     14336   // 4096 : o[b,d]

__global__ void __launch_bounds__(256, 4) fused_all(
    const float* __restrict__ x, const float* __restrict__ Wk,
    const float* __restrict__ bk, const float* __restrict__ Wv,
    const float* __restrict__ bv, float* __restrict__ ws,
    float* __restrict__ out)
{
    cg::grid_group grid = cg::this_grid();
    const int tid  = threadIdx.x;
    const int bid  = blockIdx.x;
    const int lane = tid & 63;
    const int wv   = tid >> 6;            // wave id 0..3
    __shared__ float smem[2112];          // 8.25 KB
    const float4* x4 = (const float4*)x;

    // ---------- Phase A: wbar (blocks 0..63), bbar (block 64), zero xw (65..68)
    if (bid < 64) {
        const int dloc = tid & 15, eg = tid >> 4;
        const int d = bid * 16 + dloc;
        float s = 0.f;
        for (int e = eg; e < D; e += 16) s += Wk[e * D + d];
        smem[eg * 17 + dloc] = s;
        __syncthreads();
        if (tid < 16) {
            float t = 0.f;
            #pragma unroll
            for (int i = 0; i < 16; ++i) t += smem[i * 17 + tid];
            ws[WS_WBAR + bid * 16 + tid] = t * (1.0f / D);
        }
    } else if (bid == 64) {
        smem[tid] = bk[tid] + bk[tid + 256] + bk[tid + 512] + bk[tid + 768];
        __syncthreads();
        for (int off = 128; off > 0; off >>= 1) {
            if (tid < off) smem[tid] += smem[tid + off];
            __syncthreads();
        }
        if (tid == 0) ws[WS_BBAR] = smem[0] * (1.0f / D);
    } else if (bid >= 65 && bid < 69) {
        float4* xw4 = (float4*)(ws + WS_XW);
        xw4[(bid - 65) * 256 + tid] = make_float4(0.f, 0.f, 0.f, 0.f);
    }
    grid.sync();

    // ---------- Phase B: kmean[r] = x[r,:].wbar + bbar  (4 waves/block, 2 rows/wave)
    {
        float4* sm4 = (float4*)smem;
        sm4[tid] = ((const float4*)(ws + WS_WBAR))[tid];
        __syncthreads();
        const float bbar = ws[WS_BBAR];
        const int wid = bid * 4 + wv;                 // 0..4095
        #pragma unroll
        for (int rr = 0; rr < 2; ++rr) {
            const int r = wid + rr * 4096;            // row 0..8191
            const float4* xr = x4 + (size_t)r * 256;
            float acc = 0.f;
            #pragma unroll
            for (int k = 0; k < 4; ++k) {
                const float4 xv = xr[lane + k * 64];
                const float4 wq = sm4[lane + k * 64];
                acc += xv.x * wq.x + xv.y * wq.y + xv.z * wq.z + xv.w * wq.w;
            }
            #pragma unroll
            for (int off = 32; off > 0; off >>= 1) acc += __shfl_down(acc, off);
            if (lane == 0) ws[WS_KMEAN + r] = acc + bbar;
        }
    }
    grid.sync();

    // ---------- Phase D: xw[b,d] = sum_t softmax_t * x[b,t,d]
    // block = (b = bid>>8, tc = bid&255), 8 t-rows each.
    // No max-subtraction: cos in [-1,1] => exp in [0.37,2.72], no overflow.
    {
        const int b  = bid >> 8;
        const int tc = bid & 255;
        float partial = 0.f;
        #pragma unroll
        for (int k = 0; k < 8; ++k) {
            const int i = tid + k * 256;
            const float e = expf(cosf(ws[WS_KMEAN + b * T + i]));
            smem[i] = e;
            partial += e;
        }
        #pragma unroll
        for (int off = 32; off > 0; off >>= 1) partial += __shfl_down(partial, off);
        if (lane == 0) smem[2048 + wv] = partial;
        __syncthreads();
        const float invs = 1.0f / (smem[2048] + smem[2049] + smem[2050] + smem[2051]);
        const int t0 = tc * 8;
        float4 acc = make_float4(0.f, 0.f, 0.f, 0.f);
        #pragma unroll
        for (int j = 0; j < 8; ++j) {
            const int t = t0 + j;
            const float wt = smem[t] * invs;
            const float4 xv = x4[(size_t)(b * T + t) * 256 + tid];
            acc.x += wt * xv.x; acc.y += wt * xv.y;
            acc.z += wt * xv.z; acc.w += wt * xv.w;
        }
        float* dst = ws + WS_XW + b * D + tid * 4;
        atomicAdd(dst + 0, acc.x);
        atomicAdd(dst + 1, acc.y);
        atomicAdd(dst + 2, acc.z);
        atomicAdd(dst + 3, acc.w);
    }
    grid.sync();

    // ---------- Phase E: o[b,d] = xw[b,:].Wv[d,:] + bv[d]   (block bid -> d)
    {
        const int d = bid;
        const float4 wq = ((const float4*)Wv)[d * 256 + tid];
        const float4* xw4 = (const float4*)(ws + WS_XW);
        const float4 x0 = xw4[tid], x1 = xw4[256 + tid];
        const float4 x2 = xw4[512 + tid], x3 = xw4[768 + tid];
        float a0 = wq.x * x0.x + wq.y * x0.y + wq.z * x0.z + wq.w * x0.w;
        float a1 = wq.x * x1.x + wq.y * x1.y + wq.z * x1.z + wq.w * x1.w;
        float a2 = wq.x * x2.x + wq.y * x2.y + wq.z * x2.z + wq.w * x2.w;
        float a3 = wq.x * x3.x + wq.y * x3.y + wq.z * x3.z + wq.w * x3.w;
        #pragma unroll
        for (int off = 32; off > 0; off >>= 1) {
            a0 += __shfl_down(a0, off); a1 += __shfl_down(a1, off);
            a2 += __shfl_down(a2, off); a3 += __shfl_down(a3, off);
        }
        if (lane == 0) {
            smem[2048 + wv] = a0; smem[2052 + wv] = a1;
            smem[2056 + wv] = a2; smem[2060 + wv] = a3;
        }
        __syncthreads();
        if (tid == 0) {
            const float bb = bv[d];
            ws[WS_O + 0 * D + d] = smem[2048] + smem[2049] + smem[2050] + smem[2051] + bb;
            ws[WS_O + 1 * D + d] = smem[2052] + smem[2053] + smem[2054] + smem[2055] + bb;
            ws[WS_O + 2 * D + d] = smem[2056] + smem[2057] + smem[2058] + smem[2059] + bb;
            ws[WS_O + 3 * D + d] = smem[2060] + smem[2061] + smem[2062] + smem[2063] + bb;
        }
    }
    grid.sync();

    // ---------- Phase F: out[b,t,d] = o[b,d]  (32 MiB broadcast write)
    {
        const float4* o4 = (const float4*)(ws + WS_O);
        float4* out4 = (float4*)out;
        const int idx = bid * 256 + tid;
        #pragma unroll
        for (int i = 0; i < 8; ++i) {
            const int f = idx + i * 262144;      // 2^21 float4 total
            out4[f] = o4[((f >> 19) << 8) + (f & 255)];
        }
    }
}

extern "C" void kernel_launch(void* const* d_in, const int* in_sizes, int n_in,
                              void* d_out, int out_size, void* d_ws, size_t ws_size,
                              hipStream_t stream) {
    const float* x  = (const float*)d_in[0];
    // d_in[1] = Wq, d_in[2] = bq : dead code in the reference
    const float* Wk = (const float*)d_in[3];
    const float* bk = (const float*)d_in[4];
    const float* Wv = (const float*)d_in[5];
    const float* bv = (const float*)d_in[6];
    float* ws  = (float*)d_ws;
    float* out = (float*)d_out;

    void* args[] = {(void*)&x, (void*)&Wk, (void*)&bk, (void*)&Wv,
                    (void*)&bv, (void*)&ws, (void*)&out};
    hipLaunchCooperativeKernel(reinterpret_cast<void*>(fused_all),
                               dim3(NB), dim3(256), args, 0, stream);
}

// Round 3
// 77.876 us; speedup vs baseline: 6.3811x; 6.3811x over previous
//
#include <hip/hip_runtime.h>

#define D 1024
#define T 2048
#define BATCH 4

// workspace float offsets
#define WS_PART 0      // [4][1024] : wbar partial sums (esub-major)
#define WS_BBAR 4096   // 1 float   : mean(bk)
#define WS_Z    4100   // 4 floats  : sum_t exp(cos(kmean[b,t]))
#define WS_U    4608   // 4096      : sum_t e_t * x[b,t,d]   (16B aligned)
#define WS_O    8704   // 4096      : o[b,d]

// ---- K1: wbar partials (blocks 0..255), zero u (256..259), bbar+zero Z (260)
__global__ void __launch_bounds__(256) k_prep(const float* __restrict__ Wk,
                                              const float* __restrict__ bk,
                                              float* __restrict__ ws) {
    __shared__ float smem[272];
    const int bid = blockIdx.x, tid = threadIdx.x;
    if (bid < 256) {
        const int dgrp = bid >> 2, esub = bid & 3;     // 64 d-groups x 4 e-subranges
        const int eg = tid >> 4, dloc = tid & 15;
        const int d = dgrp * 16 + dloc;
        const int e0 = esub * 256 + eg;
        float s = 0.f;
        #pragma unroll
        for (int k = 0; k < 16; ++k)
            s += Wk[(e0 + k * 16) * D + d];
        smem[eg * 17 + dloc] = s;
        __syncthreads();
        if (tid < 16) {
            float t = 0.f;
            #pragma unroll
            for (int i = 0; i < 16; ++i) t += smem[i * 17 + tid];
            ws[WS_PART + esub * 1024 + dgrp * 16 + tid] = t;
        }
    } else if (bid < 260) {
        float4* u4 = (float4*)(ws + WS_U);
        u4[(bid - 256) * 256 + tid] = make_float4(0.f, 0.f, 0.f, 0.f);
    } else {
        float sb = bk[tid] + bk[tid + 256] + bk[tid + 512] + bk[tid + 768];
        smem[tid] = sb;
        __syncthreads();
        for (int off = 128; off > 0; off >>= 1) {
            if (tid < off) smem[tid] += smem[tid + off];
            __syncthreads();
        }
        if (tid == 0) ws[WS_BBAR] = smem[0] * (1.0f / D);
        if (tid < 4) ws[WS_Z + tid] = 0.f;
    }
}

// ---- K2: single pass over x. Per row: kmean = x.wbar + bbar (block dot),
//          e = exp(cos(kmean)) [in (0.37,2.72), no max needed],
//          acc += e*x ; then atomics into u[b,:], Z[b].
// grid = 1024 blocks: b = bid>>8, 8 rows each.
__global__ void __launch_bounds__(256) k_pass(const float4* __restrict__ x4,
                                              float* __restrict__ ws) {
    __shared__ float red[8];                 // double-buffered: one sync per row
    const int bid = blockIdx.x, tid = threadIdx.x;
    const int lane = tid & 63, wv = tid >> 6;
    const int b = bid >> 8, tg = bid & 255;
    const float4* part4 = (const float4*)(ws + WS_PART);
    const float4 p0 = part4[tid],       p1 = part4[256 + tid];
    const float4 p2 = part4[512 + tid], p3 = part4[768 + tid];
    float4 wq;
    wq.x = (p0.x + p1.x + p2.x + p3.x) * (1.0f / D);
    wq.y = (p0.y + p1.y + p2.y + p3.y) * (1.0f / D);
    wq.z = (p0.z + p1.z + p2.z + p3.z) * (1.0f / D);
    wq.w = (p0.w + p1.w + p2.w + p3.w) * (1.0f / D);
    const float bbar = ws[WS_BBAR];
    const float4* xb = x4 + (size_t)(b * T + tg * 8) * (D / 4);
    float4 acc = make_float4(0.f, 0.f, 0.f, 0.f);
    float zsum = 0.f;
    for (int j = 0; j < 8; ++j) {
        const float4 xv = xb[j * 256 + tid];
        float p = xv.x * wq.x + xv.y * wq.y + xv.z * wq.z + xv.w * wq.w;
        #pragma unroll
        for (int off = 32; off > 0; off >>= 1) p += __shfl_down(p, off);
        if (lane == 0) red[(j & 1) * 4 + wv] = p;
        __syncthreads();
        const int base = (j & 1) * 4;
        const float km = red[base] + red[base + 1] + red[base + 2] + red[base + 3] + bbar;
        const float e = expf(cosf(km));
        acc.x += e * xv.x; acc.y += e * xv.y;
        acc.z += e * xv.z; acc.w += e * xv.w;
        zsum += e;
    }
    float* dst = ws + WS_U + b * D + tid * 4;
    atomicAdd(dst + 0, acc.x);
    atomicAdd(dst + 1, acc.y);
    atomicAdd(dst + 2, acc.z);
    atomicAdd(dst + 3, acc.w);
    if (tid == 0) atomicAdd(ws + WS_Z + b, zsum);
}

// ---- K3: o[b,d] = (u[b,:].Wv[d,:]) / Z[b] + bv[d] ; one wave per d
__global__ void __launch_bounds__(256) k_proj(const float4* __restrict__ Wv4,
                                              float* __restrict__ ws,
                                              const float* __restrict__ bv) {
    const int lane = threadIdx.x & 63, wv = threadIdx.x >> 6;
    const int d = blockIdx.x * 4 + wv;       // 0..1023
    const float4* u4 = (const float4*)(ws + WS_U);
    float a0 = 0.f, a1 = 0.f, a2 = 0.f, a3 = 0.f;
    #pragma unroll
    for (int k = 0; k < 4; ++k) {
        const int idx = lane + k * 64;
        const float4 wvv = Wv4[d * 256 + idx];
        const float4 x0 = u4[idx],       x1 = u4[256 + idx];
        const float4 x2 = u4[512 + idx], x3 = u4[768 + idx];
        a0 += wvv.x * x0.x + wvv.y * x0.y + wvv.z * x0.z + wvv.w * x0.w;
        a1 += wvv.x * x1.x + wvv.y * x1.y + wvv.z * x1.z + wvv.w * x1.w;
        a2 += wvv.x * x2.x + wvv.y * x2.y + wvv.z * x2.z + wvv.w * x2.w;
        a3 += wvv.x * x3.x + wvv.y * x3.y + wvv.z * x3.z + wvv.w * x3.w;
    }
    #pragma unroll
    for (int off = 32; off > 0; off >>= 1) {
        a0 += __shfl_down(a0, off); a1 += __shfl_down(a1, off);
        a2 += __shfl_down(a2, off); a3 += __shfl_down(a3, off);
    }
    if (lane == 0) {
        const float bb = bv[d];
        ws[WS_O + 0 * D + d] = a0 / ws[WS_Z + 0] + bb;
        ws[WS_O + 1 * D + d] = a1 / ws[WS_Z + 1] + bb;
        ws[WS_O + 2 * D + d] = a2 / ws[WS_Z + 2] + bb;
        ws[WS_O + 3 * D + d] = a3 / ws[WS_Z + 3] + bb;
    }
}

// ---- K4: out[b,t,d] = o[b,d]  (32 MiB coalesced broadcast write)
__global__ void __launch_bounds__(256) k_bcast(const float* __restrict__ ws,
                                               float4* __restrict__ out4) {
    const float4* o4 = (const float4*)(ws + WS_O);
    const int idx = blockIdx.x * 256 + threadIdx.x;   // 0..524287
    #pragma unroll
    for (int i = 0; i < 4; ++i) {
        const int f = idx + i * 524288;               // 2^21 float4 total
        out4[f] = o4[((f >> 19) << 8) + (f & 255)];   // b = f>>19, d4 = f&255
    }
}

extern "C" void kernel_launch(void* const* d_in, const int* in_sizes, int n_in,
                              void* d_out, int out_size, void* d_ws, size_t ws_size,
                              hipStream_t stream) {
    const float* x  = (const float*)d_in[0];
    // d_in[1] = Wq, d_in[2] = bq : dead code in the reference
    const float* Wk = (const float*)d_in[3];
    const float* bk = (const float*)d_in[4];
    const float* Wv = (const float*)d_in[5];
    const float* bv = (const float*)d_in[6];
    float* ws  = (float*)d_ws;
    float* out = (float*)d_out;

    k_prep <<<261, 256, 0, stream>>>(Wk, bk, ws);
    k_pass <<<1024, 256, 0, stream>>>((const float4*)x, ws);
    k_proj <<<256, 256, 0, stream>>>((const float4*)Wv, ws, bv);
    k_bcast<<<2048, 256, 0, stream>>>(ws, (float4*)out);
}

// Round 4
// 33.474 us; speedup vs baseline: 14.8453x; 2.3265x over previous
//
#include <hip/hip_runtime.h>

#define D 1024
#define T 2048
#define BATCH 4

// workspace float offsets
#define WS_PARTW 0        // [4][1024] : wbar partial sums (esub-major)
#define WS_BBAR  4096     // 1 float   : mean(bk)
#define WS_Z     4100     // 4 floats  : Z[b] = sum_t exp(cos(kmean))
#define WS_ZP    4608     // 1024      : per-block Z partials
#define WS_U     5632     // 4096      : u[b][d] = sum_t e_t*x[b,t,d]
#define WS_O     10240    // 4096      : o[b][d]
#define WS_PART  16384    // [4][256][1024] : per-block u partials (4 MB)
#define WS_NEED  (((size_t)WS_PART + 1024 * 1024) * 4)

// ---- K1: wbar partials (blocks 0..63, float4 loads), bbar+zero Z (64), zero u (65)
__global__ void __launch_bounds__(256) k_prep(const float4* __restrict__ Wk4,
                                              const float* __restrict__ bk,
                                              float* __restrict__ ws) {
    __shared__ float4 sm[16][17];
    __shared__ float red[256];
    const int bid = blockIdx.x, tid = threadIdx.x;
    if (bid < 64) {
        const int dchunk = bid >> 2, esub = bid & 3;   // 16 d-chunks x 4 e-subranges
        const int fc = tid & 15, eg = tid >> 4;
        float4 s = make_float4(0.f, 0.f, 0.f, 0.f);
        #pragma unroll
        for (int k = 0; k < 16; ++k) {
            const int e = esub * 256 + eg + k * 16;
            const float4 v = Wk4[e * 256 + dchunk * 16 + fc];
            s.x += v.x; s.y += v.y; s.z += v.z; s.w += v.w;
        }
        sm[eg][fc] = s;
        __syncthreads();
        if (tid < 16) {
            float4 t = make_float4(0.f, 0.f, 0.f, 0.f);
            #pragma unroll
            for (int g = 0; g < 16; ++g) {
                const float4 v = sm[g][tid];
                t.x += v.x; t.y += v.y; t.z += v.z; t.w += v.w;
            }
            ((float4*)(ws + WS_PARTW))[esub * 256 + dchunk * 16 + tid] = t;
        }
    } else if (bid == 64) {
        red[tid] = bk[tid] + bk[tid + 256] + bk[tid + 512] + bk[tid + 768];
        __syncthreads();
        for (int off = 128; off > 0; off >>= 1) {
            if (tid < off) red[tid] += red[tid + off];
            __syncthreads();
        }
        if (tid == 0) ws[WS_BBAR] = red[0] * (1.0f / D);
        if (tid < 4) ws[WS_Z + tid] = 0.f;
    } else {
        float4* u4 = (float4*)(ws + WS_U);
        u4[tid] = make_float4(0.f, 0.f, 0.f, 0.f);
        u4[256 + tid] = make_float4(0.f, 0.f, 0.f, 0.f);
        u4[512 + tid] = make_float4(0.f, 0.f, 0.f, 0.f);
        u4[768 + tid] = make_float4(0.f, 0.f, 0.f, 0.f);
    }
}

// ---- K2: single pass over x, batched 8 rows per block, ONE sync, no hot atomics.
// block bid = b*256 + tc handles rows tc*8..tc*8+7 of batch b.
template <bool USE_PART>
__global__ void __launch_bounds__(256) k_pass(const float4* __restrict__ x4,
                                              float* __restrict__ ws) {
    __shared__ float lds[4][8];
    const int tid = threadIdx.x, lane = tid & 63, w = tid >> 6;
    const int bid = blockIdx.x;
    const int b = bid >> 8, tc = bid & 255;

    // wbar[tid] (float4) from the 4 e-subrange partials
    const float4* pw = (const float4*)(ws + WS_PARTW);
    const float4 p0 = pw[tid],       p1 = pw[256 + tid];
    const float4 p2 = pw[512 + tid], p3 = pw[768 + tid];
    float4 wq;
    wq.x = (p0.x + p1.x + p2.x + p3.x) * (1.0f / D);
    wq.y = (p0.y + p1.y + p2.y + p3.y) * (1.0f / D);
    wq.z = (p0.z + p1.z + p2.z + p3.z) * (1.0f / D);
    wq.w = (p0.w + p1.w + p2.w + p3.w) * (1.0f / D);
    const float bbar = ws[WS_BBAR];

    // phase 1: load all 8 rows (independent -> deep ILP), dot partials
    const float4* xr = x4 + (size_t)(b * T + tc * 8) * 256;
    float4 xv[8];
    #pragma unroll
    for (int j = 0; j < 8; ++j) xv[j] = xr[j * 256 + tid];
    float p[8];
    #pragma unroll
    for (int j = 0; j < 8; ++j)
        p[j] = xv[j].x * wq.x + xv[j].y * wq.y + xv[j].z * wq.z + xv[j].w * wq.w;

    // phase 2: batched block reduction of the 8 dots, one sync
    #pragma unroll
    for (int off = 32; off > 0; off >>= 1) {
        #pragma unroll
        for (int j = 0; j < 8; ++j) p[j] += __shfl_down(p[j], off);
    }
    if (lane == 0) {
        #pragma unroll
        for (int j = 0; j < 8; ++j) lds[w][j] = p[j];
    }
    __syncthreads();

    float e[8];
    float zs = 0.f;
    #pragma unroll
    for (int j = 0; j < 8; ++j) {
        const float km = lds[0][j] + lds[1][j] + lds[2][j] + lds[3][j] + bbar;
        e[j] = expf(cosf(km));   // cos in [-1,1] -> exp in (0.36,2.72): no max needed
        zs += e[j];
    }
    float4 acc = make_float4(0.f, 0.f, 0.f, 0.f);
    #pragma unroll
    for (int j = 0; j < 8; ++j) {
        acc.x += e[j] * xv[j].x; acc.y += e[j] * xv[j].y;
        acc.z += e[j] * xv[j].z; acc.w += e[j] * xv[j].w;
    }

    if (USE_PART) {
        ((float4*)(ws + WS_PART))[(size_t)bid * 256 + tid] = acc;  // [b][tc][d4]
        if (tid == 0) ws[WS_ZP + bid] = zs;
    } else {
        float* dst = ws + WS_U + b * D + tid * 4;
        atomicAdd(dst + 0, acc.x);
        atomicAdd(dst + 1, acc.y);
        atomicAdd(dst + 2, acc.z);
        atomicAdd(dst + 3, acc.w);
        if (tid == 0) atomicAdd(ws + WS_Z + b, zs);
    }
}

// ---- K3: u[b][d4] = sum_p part[b][p][d4] ; Z[b] = sum_p Zpart  (64 blocks)
__global__ void __launch_bounds__(256) k_reduce(float* __restrict__ ws) {
    __shared__ float4 sm[16][17];
    __shared__ float zr[4];
    const int bid = blockIdx.x, tid = threadIdx.x;
    const int b = bid >> 4, dc = bid & 15;
    const int dl = tid & 15, pg = tid >> 4;
    const float4* part = (const float4*)(ws + WS_PART) + (size_t)b * 65536;
    float4 s = make_float4(0.f, 0.f, 0.f, 0.f);
    #pragma unroll
    for (int k = 0; k < 16; ++k) {
        const float4 v = part[(pg * 16 + k) * 256 + dc * 16 + dl];
        s.x += v.x; s.y += v.y; s.z += v.z; s.w += v.w;
    }
    sm[pg][dl] = s;
    __syncthreads();
    if (tid < 16) {
        float4 t = make_float4(0.f, 0.f, 0.f, 0.f);
        #pragma unroll
        for (int g = 0; g < 16; ++g) {
            const float4 v = sm[g][tid];
            t.x += v.x; t.y += v.y; t.z += v.z; t.w += v.w;
        }
        ((float4*)(ws + WS_U))[b * 256 + dc * 16 + tid] = t;
    }
    if (dc == 0) {
        float z = ws[WS_ZP + b * 256 + tid];
        #pragma unroll
        for (int off = 32; off > 0; off >>= 1) z += __shfl_down(z, off);
        if ((tid & 63) == 0) zr[tid >> 6] = z;
        __syncthreads();
        if (tid == 0) ws[WS_Z + b] = zr[0] + zr[1] + zr[2] + zr[3];
    }
}

// ---- K4: o[b,d] = (u[b,:].Wv[d,:]) / Z[b] + bv[d] ; one wave per d
__global__ void __launch_bounds__(256) k_proj(const float4* __restrict__ Wv4,
                                              float* __restrict__ ws,
                                              const float* __restrict__ bv) {
    const int lane = threadIdx.x & 63, w = threadIdx.x >> 6;
    const int d = blockIdx.x * 4 + w;        // 0..1023
    const float4* u4 = (const float4*)(ws + WS_U);
    float a0 = 0.f, a1 = 0.f, a2 = 0.f, a3 = 0.f;
    #pragma unroll
    for (int k = 0; k < 4; ++k) {
        const int idx = lane + k * 64;
        const float4 wvv = Wv4[d * 256 + idx];
        const float4 x0 = u4[idx],       x1 = u4[256 + idx];
        const float4 x2 = u4[512 + idx], x3 = u4[768 + idx];
        a0 += wvv.x * x0.x + wvv.y * x0.y + wvv.z * x0.z + wvv.w * x0.w;
        a1 += wvv.x * x1.x + wvv.y * x1.y + wvv.z * x1.z + wvv.w * x1.w;
        a2 += wvv.x * x2.x + wvv.y * x2.y + wvv.z * x2.z + wvv.w * x2.w;
        a3 += wvv.x * x3.x + wvv.y * x3.y + wvv.z * x3.z + wvv.w * x3.w;
    }
    #pragma unroll
    for (int off = 32; off > 0; off >>= 1) {
        a0 += __shfl_down(a0, off); a1 += __shfl_down(a1, off);
        a2 += __shfl_down(a2, off); a3 += __shfl_down(a3, off);
    }
    if (lane == 0) {
        const float bb = bv[d];
        ws[WS_O + 0 * D + d] = a0 / ws[WS_Z + 0] + bb;
        ws[WS_O + 1 * D + d] = a1 / ws[WS_Z + 1] + bb;
        ws[WS_O + 2 * D + d] = a2 / ws[WS_Z + 2] + bb;
        ws[WS_O + 3 * D + d] = a3 / ws[WS_Z + 3] + bb;
    }
}

// ---- K5: out[b,t,d] = o[b,d]  (32 MiB coalesced broadcast write)
__global__ void __launch_bounds__(256) k_bcast(const float* __restrict__ ws,
                                               float4* __restrict__ out4) {
    const float4* o4 = (const float4*)(ws + WS_O);
    const int idx = blockIdx.x * 256 + threadIdx.x;   // 0..524287
    #pragma unroll
    for (int i = 0; i < 4; ++i) {
        const int f = idx + i * 524288;               // 2^21 float4 total
        out4[f] = o4[((f >> 19) << 8) + (f & 255)];   // b = f>>19, d4 = f&255
    }
}

extern "C" void kernel_launch(void* const* d_in, const int* in_sizes, int n_in,
                              void* d_out, int out_size, void* d_ws, size_t ws_size,
                              hipStream_t stream) {
    const float* x  = (const float*)d_in[0];
    // d_in[1] = Wq, d_in[2] = bq : dead code in the reference
    const float* Wk = (const float*)d_in[3];
    const float* bk = (const float*)d_in[4];
    const float* Wv = (const float*)d_in[5];
    const float* bv = (const float*)d_in[6];
    float* ws  = (float*)d_ws;
    float* out = (float*)d_out;

    const bool use_part = ws_size >= WS_NEED;

    k_prep<<<66, 256, 0, stream>>>((const float4*)Wk, bk, ws);
    if (use_part) {
        k_pass<true><<<1024, 256, 0, stream>>>((const float4*)x, ws);
        k_reduce<<<64, 256, 0, stream>>>(ws);
    } else {
        k_pass<false><<<1024, 256, 0, stream>>>((const float4*)x, ws);
    }
    k_proj<<<256, 256, 0, stream>>>((const float4*)Wv, ws, bv);
    k_bcast<<<2048, 256, 0, stream>>>(ws, (float4*)out);
}